// Round 2
// baseline (66.170 us; speedup 1.0000x reference)
//
#include <hip/hip_runtime.h>

// ComplexUpSampling2D: B=16, H=W=128, C=64, 2x2 nearest upsample.
// Source pixel for output (oh, ow) is (oh>>1, ow>>1).
//
// The harness's out_size disambiguates the expected layout:
//   67,108,864  -> real part only, [16,256,256,64] float32 (256 MiB)
//  134,217,728  -> interleaved complex (re,im) pairs       (512 MiB)
// We dispatch on it so we never write past the allocated buffer.

// ---- Path A: real part only, output-centric, fully coalesced stores ----
__global__ __launch_bounds__(256) void upsample_real_kernel(
    const float* __restrict__ xre,
    float* __restrict__ out)
{
    const int tid  = blockIdx.x * 256 + threadIdx.x;  // 0 .. 16,777,215 (one float4 each)
    const int c4   = tid & 15;                        // float4 index within 64-channel pixel
    const int opix = tid >> 4;                        // output pixel 0 .. 1,048,575
    const int ow   = opix & 255;
    const int oh   = (opix >> 8) & 255;
    const int b    = opix >> 16;

    const int ipix = ((b << 7) + (oh >> 1)) * 128 + (ow >> 1);
    const float4 v = *reinterpret_cast<const float4*>(
        xre + ((size_t)ipix << 6) + (c4 << 2));
    *reinterpret_cast<float4*>(out + ((size_t)tid << 2)) = v;
}

// ---- Path B: interleaved complex, input-centric (each input byte read once) ----
__global__ __launch_bounds__(256) void upsample_cplx_kernel(
    const float* __restrict__ xre,
    const float* __restrict__ xim,
    float* __restrict__ out)
{
    const int tid   = blockIdx.x * 256 + threadIdx.x;  // 0 .. 8,388,607
    const int chunk = tid & 31;                        // 2-channel chunk
    const int pix   = tid >> 5;                        // input pixel
    const int w     = pix & 127;
    const int h     = (pix >> 7) & 127;
    const int b     = pix >> 14;

    const float2 re = *reinterpret_cast<const float2*>(xre + ((size_t)pix << 6) + (chunk << 1));
    const float2 im = *reinterpret_cast<const float2*>(xim + ((size_t)pix << 6) + (chunk << 1));
    const float4 v  = make_float4(re.x, im.x, re.y, im.y);

    const int orow = ((b << 8) + (h << 1)) * 256 + (w << 1);  // output pixel index
    float* o = out + ((size_t)orow << 7) + (chunk << 2);      // 128 floats per output pixel

    *reinterpret_cast<float4*>(o)                   = v;
    *reinterpret_cast<float4*>(o + 128)             = v;
    *reinterpret_cast<float4*>(o + 256 * 128)       = v;
    *reinterpret_cast<float4*>(o + 256 * 128 + 128) = v;
}

extern "C" void kernel_launch(void* const* d_in, const int* in_sizes, int n_in,
                              void* d_out, int out_size, void* d_ws, size_t ws_size,
                              hipStream_t stream) {
    const float* xre = (const float*)d_in[0];
    const float* xim = (const float*)d_in[1];
    float* out = (float*)d_out;

    if (out_size >= 134217728) {
        // Interleaved complex layout (512 MiB buffer).
        const int threads = 16 * 128 * 128 * 32;  // 8,388,608
        hipLaunchKernelGGL(upsample_cplx_kernel, dim3(threads / 256), dim3(256), 0, stream,
                           xre, xim, out);
    } else {
        // Real-part-only layout (256 MiB buffer): out_size == 67,108,864.
        const int threads = out_size / 4;          // one float4 per thread
        hipLaunchKernelGGL(upsample_real_kernel, dim3(threads / 256), dim3(256), 0, stream,
                           xre, out);
    }
}

// Round 4
// 51.637 us; speedup vs baseline: 1.2814x; 1.2814x over previous
//
#include <hip/hip_runtime.h>

// ComplexUpSampling2D: B=16, H=W=128, C=64, 2x2 nearest upsample.
// Harness expects REAL PART ONLY: [16,256,256,64] f32, out_size = 67,108,864
// (proven R2: 66 us is only feasible for the 256 MiB layout).
//
// Row-pair input-centric kernel: thread = one float4 column j of one output
// row-pair (source row h -> output rows 2h, 2h+1). Each thread:
//   - loads its source float4 exactly once (64 MiB total HBM reads)
//   - nt-stores it to rows 2h and 2h+1 at the same column
// Every store: 64 lanes x 16 B = 1024 B contiguous. Output is write-once ->
// non-temporal so it doesn't evict the input stream from L2.

typedef float f32x4 __attribute__((ext_vector_type(4)));  // native vec: nt builtin OK

__global__ __launch_bounds__(256) void upsample_real_rowpair(
    const float* __restrict__ xre,
    float* __restrict__ out)
{
    const int tid = blockIdx.x * 256 + threadIdx.x;  // 0 .. 8,388,607
    const int j   = tid & 4095;                      // float4 col within output row
    const int row = tid >> 12;                       // b*128 + h, 0 .. 2047

    // source: input pixel (row, j>>5), float4 chunk j&15
    const f32x4 v = reinterpret_cast<const f32x4*>(xre)[
        ((size_t)row << 11) + (size_t)((j >> 5) << 4) + (j & 15)];

    const int b = row >> 7;
    const int h = row & 127;
    const size_t orow = (size_t)(b * 256 + (h << 1));              // output row index
    f32x4* o = reinterpret_cast<f32x4*>(out) + (orow << 12) + j;   // 4096 float4/row

    __builtin_nontemporal_store(v, o);          // row 2h
    __builtin_nontemporal_store(v, o + 4096);   // row 2h+1
}

// Fallback: interleaved complex layout (kept for safety; not expected).
__global__ __launch_bounds__(256) void upsample_cplx_kernel(
    const float* __restrict__ xre,
    const float* __restrict__ xim,
    float* __restrict__ out)
{
    const int tid   = blockIdx.x * 256 + threadIdx.x;
    const int chunk = tid & 31;
    const int pix   = tid >> 5;
    const int w     = pix & 127;
    const int h     = (pix >> 7) & 127;
    const int b     = pix >> 14;

    const float2 re = *reinterpret_cast<const float2*>(xre + ((size_t)pix << 6) + (chunk << 1));
    const float2 im = *reinterpret_cast<const float2*>(xim + ((size_t)pix << 6) + (chunk << 1));
    const float4 v  = make_float4(re.x, im.x, re.y, im.y);

    const int orow = ((b << 8) + (h << 1)) * 256 + (w << 1);
    float* o = out + ((size_t)orow << 7) + (chunk << 2);

    *reinterpret_cast<float4*>(o)                   = v;
    *reinterpret_cast<float4*>(o + 128)             = v;
    *reinterpret_cast<float4*>(o + 256 * 128)       = v;
    *reinterpret_cast<float4*>(o + 256 * 128 + 128) = v;
}

extern "C" void kernel_launch(void* const* d_in, const int* in_sizes, int n_in,
                              void* d_out, int out_size, void* d_ws, size_t ws_size,
                              hipStream_t stream) {
    const float* xre = (const float*)d_in[0];
    const float* xim = (const float*)d_in[1];
    float* out = (float*)d_out;

    if (out_size >= 134217728) {
        const int threads = 16 * 128 * 128 * 32;
        hipLaunchKernelGGL(upsample_cplx_kernel, dim3(threads / 256), dim3(256), 0, stream,
                           xre, xim, out);
    } else {
        // real path: 8,388,608 threads, one float4 load + two nt float4 stores each
        hipLaunchKernelGGL(upsample_real_rowpair, dim3(32768), dim3(256), 0, stream,
                           xre, out);
    }
}